// Round 6
// baseline (391.462 us; speedup 1.0000x reference)
//
#include <hip/hip_runtime.h>
#include <hip/hip_bf16.h>
#include <stdint.h>

// S5 layer: L=16384, H=1024, P=1024. fp32 in/out. Round-13:
//   - Rounds 8-12 post-mortem: four different schedules all pin MfmaUtil at
//     28-31%. DS-read service (~2300 cyc/tile/CU) and MFMA (~2480) run
//     SERIALIZED because every wave's phase shape is read-burst -> drain ->
//     MFMA-burst and all waves phase-lock. Fix: within-wave one-PHASE-ahead
//     register pipelining with counted lgkmcnt:
//       P0: issue afL,b0,b1(16) -> lgkm(4)  -> MMA(afL,b0)
//       P1: issue afH(8)        -> lgkm(8)  -> MMA(afL,b1)
//       P2: lgkm(0)[free] -> barrier -> stage(t+2) h0,h2 -> MMA(afH,b1)
//       P3: stage(t+2) h1,h3 -> MMA(afH,b0) -> vmcnt(8) -> barrier
//     Reads for the NEXT phase are serviced by the DS unit WHILE the current
//     MFMA cluster runs (within-wave ILP; no reliance on partner waves).
//     Frag live set 48 VGPR (afL/afH/b0/b1) + acc 128 in AGPR side: fits the
//     128/128 split at 2 waves/SIMD (r9's spill was 96 frag VGPR).
//     2 barriers/tile; one exposed 12-read drain per tile (P0).
//   - kept: 256x256 block, BK=64, 8 waves 2Mx4N (wave tile 128x64), dbuf
//     LDS, XOR bank swizzle via pre-swizzled global src, XCD swizzle,
//     setprio, counted vmcnt staging (1.5-tile lead), MODE1 fused chunk
//     aggregates, MODE2 fused D-residual epilogue, scan kernels, prep.

#define L_SEQ 16384
#define H_DIM 1024
#define P_DIM 1024
#define NCH   256
#define TCH   64

typedef __bf16 bf16x8 __attribute__((ext_vector_type(8)));
typedef float  floatx4 __attribute__((ext_vector_type(4)));
using bf16 = __hip_bfloat16;

__device__ __forceinline__ void gld_lds16(const void* g, void* l) {
    __builtin_amdgcn_global_load_lds(
        (const __attribute__((address_space(1))) uint32_t*)g,
        (__attribute__((address_space(3))) uint32_t*)l, 16, 0, 0);
}

__device__ __forceinline__ float lo_bf(uint32_t v) { return __uint_as_float(v << 16); }
__device__ __forceinline__ float hi_bf(uint32_t v) { return __uint_as_float(v & 0xffff0000u); }
__device__ __forceinline__ uint32_t pack_bf(float r, float i) {
    bf16 rb = __float2bfloat16(r), ib = __float2bfloat16(i);
    return ((uint32_t)(*(uint16_t*)&ib) << 16) | (uint32_t)(*(uint16_t*)&rb);
}

__device__ __forceinline__ float rd(const void* p, size_t i, int f) {
    return f ? ((const float*)p)[i]
             : __bfloat162float(((const bf16*)p)[i]);
}

// per-block dtype self-detect (fp32 halfwords read as bf16 show |x|>=128)
__device__ __forceinline__ int detect_f32(const uint16_t* u) {
    __shared__ int cnt;
    if (threadIdx.x == 0) cnt = 0;
    __syncthreads();
    int c = 0;
    #pragma unroll
    for (int i = 0; i < 8; ++i) {
        int e = (u[threadIdx.x * 8 + i] >> 7) & 0xFF;
        c += (e >= 134);
    }
    if (c) atomicAdd(&cnt, c);
    __syncthreads();
    return cnt > 32;
}

// ---------------------------------------------------------------- convert u
__global__ void convert_u(const void* __restrict__ uin, bf16* __restrict__ ub) {
    const int f = detect_f32((const uint16_t*)uin);
    const size_t g = (size_t)blockIdx.x * 256 + threadIdx.x;
    if (f) {
        const float4* s = (const float4*)uin + g * 2;
        float4 a = s[0], b = s[1];
        alignas(16) bf16 t[8] = {
            __float2bfloat16(a.x), __float2bfloat16(a.y),
            __float2bfloat16(a.z), __float2bfloat16(a.w),
            __float2bfloat16(b.x), __float2bfloat16(b.y),
            __float2bfloat16(b.z), __float2bfloat16(b.w)};
        ((uint4*)ub)[g] = *(const uint4*)t;
    } else {
        ((uint4*)ub)[g] = ((const uint4*)uin)[g];
    }
}

// ---------------------------------------------------------------- prep (fused)
__global__ void prep_all(const void* __restrict__ u,
                         const void* __restrict__ Lre, const void* __restrict__ Lim,
                         const void* __restrict__ lstep, const void* __restrict__ B,
                         const void* __restrict__ C, const void* __restrict__ D,
                         bf16* __restrict__ W1t, bf16* __restrict__ W2t,
                         float* __restrict__ d_f,
                         float2* __restrict__ lam, float2* __restrict__ lamT) {
    const int f = detect_f32((const uint16_t*)u);
    const int p = blockIdx.x;
    float lr = fminf(rd(Lre, p, f), -1e-4f);
    float li = rd(Lim, p, f);
    float s  = expf(rd(lstep, p, f));
    float ea = expf(lr * s);
    float lbr = ea * cosf(li * s), lbi = ea * sinf(li * s);   // lambda_bar
    float dr = lbr - 1.0f, di = lbi;
    float den = lr * lr + li * li;
    float cr = (dr * lr + di * li) / den;                     // (lb-1)/Lambda
    float ci = (di * lr - dr * li) / den;
    if (threadIdx.x == 0) {
        lam[p] = make_float2(lbr, lbi);
        float tr = lbr, ti = lbi;                             // lambda_bar^64
        #pragma unroll
        for (int q = 0; q < 6; ++q) {
            float nr = tr * tr - ti * ti, ni = 2.0f * tr * ti;
            tr = nr; ti = ni;
        }
        lamT[p] = make_float2(tr, ti);
        d_f[p] = rd(D, p, f);
    }
    for (int h = threadIdx.x; h < H_DIM; h += blockDim.x) {
        size_t base = ((size_t)p * H_DIM + h) * 2;
        float br = rd(B, base + 0, f);
        float bi = rd(B, base + 1, f);
        W1t[(size_t)(2 * p)     * H_DIM + h] = __float2bfloat16(cr * br - ci * bi);
        W1t[(size_t)(2 * p + 1) * H_DIM + h] = __float2bfloat16(cr * bi + ci * br);
    }
    const int h = blockIdx.x;
    for (int q = threadIdx.x; q < P_DIM; q += blockDim.x) {
        size_t base = ((size_t)h * P_DIM + q) * 2;
        W2t[(size_t)h * (2 * P_DIM) + 2 * q]     = __float2bfloat16( 2.0f * rd(C, base + 0, f));
        W2t[(size_t)h * (2 * P_DIM) + 2 * q + 1] = __float2bfloat16(-2.0f * rd(C, base + 1, f));
    }
}

// ---------------------------------------------------------------- GEMM 256x256
// A(M,K) bf16 rm, Bt(N,K) bf16 rm. 256x256 block, BK=64, 8 waves (2Mx4N),
// wave tile 128x64. One-phase-ahead register pipeline with counted lgkm
// (see header). MODE 1: OutBF bf16 + fused chunk aggregates.
// MODE 2: OutF fp32 = acc + U*Dvec, nontemporal.

#define SB0 __builtin_amdgcn_sched_barrier(0)

// stage one 16KB half-tile: h=0 A rows 0-127, h=1 A rows 128-255,
// h=2 B rows 0-127, h=3 B rows 128-255. 2 gld_lds per thread.
#define STAGEH(b, t, h) do {                                                  \
    const int k0_ = (t) * 64;                                                 \
    _Pragma("unroll")                                                         \
    for (int q_ = 0; q_ < 2; ++q_) {                                          \
        const int row_ = ((h) & 1) * 128 + q_ * 64 + srow;                    \
        const int g_   = sg ^ (row_ & 7);                                     \
        if ((h) < 2)                                                          \
            gld_lds16(A + (size_t)(bm + row_) * K + k0_ + g_ * 8,             \
                      sA + (b) * 32768 + ((h) & 1) * 16384 + q_ * 8192 + wave * 1024); \
        else                                                                  \
            gld_lds16(Bt + (size_t)(bn + row_) * K + k0_ + g_ * 8,            \
                      sB + (b) * 32768 + ((h) & 1) * 16384 + q_ * 8192 + wave * 1024); \
    } } while (0)

// load 4 A-fragment rows (mh half) into dst[4][2]
#define LDA_TO(dst, b, mh) do {                                               \
    _Pragma("unroll")                                                         \
    for (int mi_ = 0; mi_ < 4; ++mi_) {                                       \
        const int row_ = wm + ((mh) * 4 + mi_) * 16 + fr;                     \
        _Pragma("unroll")                                                     \
        for (int ks_ = 0; ks_ < 2; ++ks_) {                                   \
            const int ch_ = (ks_ * 4 + kq) ^ (row_ & 7);                      \
            dst[mi_][ks_] = *(const bf16x8*)(sA + (b) * 32768 + row_ * 128 + ch_ * 16); \
        } } } while (0)

// load 2 B-fragment rows (nh half) into dst[2][2]
#define LDB_TO(dst, b, nh) do {                                               \
    _Pragma("unroll")                                                         \
    for (int ni_ = 0; ni_ < 2; ++ni_) {                                       \
        const int row_ = wn + ((nh) * 2 + ni_) * 16 + fr;                     \
        _Pragma("unroll")                                                     \
        for (int ks_ = 0; ks_ < 2; ++ks_) {                                   \
            const int ch_ = (ks_ * 4 + kq) ^ (row_ & 7);                      \
            dst[ni_][ks_] = *(const bf16x8*)(sB + (b) * 32768 + row_ * 128 + ch_ * 16); \
        } } } while (0)

#define MMA(afv, bfv, mh, nh) do {                                            \
    __builtin_amdgcn_s_setprio(1);                                            \
    _Pragma("unroll")                                                         \
    for (int mi_ = 0; mi_ < 4; ++mi_)                                         \
        _Pragma("unroll")                                                     \
        for (int ni_ = 0; ni_ < 2; ++ni_)                                     \
            _Pragma("unroll")                                                 \
            for (int ks_ = 0; ks_ < 2; ++ks_)                                 \
                acc[(mh) * 4 + mi_][(nh) * 2 + ni_] =                         \
                    __builtin_amdgcn_mfma_f32_16x16x32_bf16(                  \
                        afv[mi_][ks_], bfv[ni_][ks_],                         \
                        acc[(mh) * 4 + mi_][(nh) * 2 + ni_], 0, 0, 0);        \
    __builtin_amdgcn_s_setprio(0);                                            \
} while (0)

template <int N, int K, int MODE>
__global__ __launch_bounds__(512, 2) void gemm256(
    const bf16* __restrict__ A, const bf16* __restrict__ Bt,
    bf16* __restrict__ OutBF, float* __restrict__ OutF,
    const bf16* __restrict__ U, const float* __restrict__ Dvec,
    const float2* __restrict__ lam, float2* __restrict__ aggp) {
    constexpr int NXB = N / 256;
    constexpr int KT  = K / 64;
    __shared__ alignas(16) uint8_t sA[2 * 32768];   // [buf][256 rows][128 B]
    __shared__ alignas(16) uint8_t sB[2 * 32768];

    const int tid  = threadIdx.x;
    const int wave = tid >> 6;
    const int lane = tid & 63;
    const int bid  = blockIdx.x;
    const int xr   = bid & 7;
    const int jj   = bid >> 3;
    const int bx   = jj % NXB;
    const int by   = (jj / NXB) * 8 + xr;
    const int bm   = by * 256, bn = bx * 256;
    const int wm   = (wave >> 2) * 128, wn = (wave & 3) * 64;

    floatx4 acc[8][4] = {};

    const int fr   = lane & 15;
    const int kq   = lane >> 4;        // 0..3
    const int srow = tid >> 3;         // 0..63
    const int sg   = tid & 7;

    // prologue: stage tiles 0 and 1 fully; vmcnt(8) = tile 0 landed.
    STAGEH(0, 0, 0); STAGEH(0, 0, 1); STAGEH(0, 0, 2); STAGEH(0, 0, 3);
    STAGEH(1, 1, 0); STAGEH(1, 1, 1); STAGEH(1, 1, 2); STAGEH(1, 1, 3);
    asm volatile("s_waitcnt vmcnt(8)" ::: "memory");
    SB0;
    __builtin_amdgcn_s_barrier();

    bf16x8 afL[4][2], afH[4][2], b0[2][2], b1[2][2];

    #pragma unroll 2
    for (int t = 0; t < KT; ++t) {
        const int cur = t & 1;
        // ---- P0: issue 16 reads (afL 8, b0 4, b1 4), wait oldest 12
        LDA_TO(afL, cur, 0); SB0;
        LDB_TO(b0, cur, 0);  SB0;
        LDB_TO(b1, cur, 1);  SB0;
        asm volatile("s_waitcnt lgkmcnt(4)" ::: "memory");  // afL,b0 ready
        SB0;
        MMA(afL, b0, 0, 0);
        // ---- P1: issue afH (8 reads); wait until only they are outstanding
        LDA_TO(afH, cur, 1); SB0;
        asm volatile("s_waitcnt lgkmcnt(8)" ::: "memory");  // b1 ready
        SB0;
        MMA(afL, b1, 0, 1);
        // ---- P2: afH ready (issued one MFMA-cluster ago); all reads of
        //          buf[cur] serviced -> barrier -> overwrite-stage t+2
        asm volatile("s_waitcnt lgkmcnt(0)" ::: "memory");
        SB0;
        __builtin_amdgcn_s_barrier();
        if (t + 2 < KT) { STAGEH(cur, t + 2, 0); STAGEH(cur, t + 2, 2); }
        SB0;
        MMA(afH, b1, 1, 1);
        // ---- P3: stage rest of t+2, last MFMA cluster, confirm t+1 landed
        if (t + 2 < KT) { STAGEH(cur, t + 2, 1); STAGEH(cur, t + 2, 3); }
        SB0;
        MMA(afH, b0, 1, 0);
        if (t + 2 < KT) {
            asm volatile("s_waitcnt vmcnt(8)" ::: "memory");  // t+1 landed
        } else {
            asm volatile("s_waitcnt vmcnt(0)" ::: "memory");  // final drain
        }
        SB0;
        __builtin_amdgcn_s_barrier();
    }

    // ---- C write ----
    const int col0  = bn + wn + fr;
    const int rbase = bm + wm + kq * 4;
    #pragma unroll
    for (int mi = 0; mi < 8; ++mi) {
        #pragma unroll
        for (int rr = 0; rr < 4; ++rr) {
            const int row = rbase + mi * 16 + rr;
            #pragma unroll
            for (int ni = 0; ni < 4; ++ni) {
                const int c = col0 + ni * 16;
                float v = acc[mi][ni][rr];
                if (MODE == 2) {
                    float uu = __bfloat162float(U[(size_t)row * H_DIM + c]);
                    __builtin_nontemporal_store(v + uu * Dvec[c],
                                                &OutF[(size_t)row * N + c]);
                } else {
                    OutBF[(size_t)row * N + c] = __float2bfloat16(v);
                }
            }
        }
    }

    if (MODE == 1) {
        // ---- fused phase1: agg_cg(p) = sum_t lam_p^(63-t) * Bu_t(p) ----
        // Wave spans 2 chunks of 64 rows (half h: mi 4h..4h+3). Within a
        // chunk t = mi2*16 + kq*4 + rr; register-only weights: w starts at
        // lam^(12-4kq), *= lam per t-step, *= lam^12 between mi2 groups.
        // Even lane holds re, odd lane im (interleaved cols).
        const int par = fr & 1;
        const int cg0 = (bm + wm) >> 6;
        #pragma unroll
        for (int ni = 0; ni < 4; ++ni) {
            const int ql = (wn + ni * 16 + (fr & ~1)) >> 1;   // 0..127
            const float2 lb = lam[(bn >> 1) + ql];
            const float l1r = lb.x, l1i = lb.y;
            const float l2r = l1r * l1r - l1i * l1i, l2i = 2.f * l1r * l1i;
            const float l4r = l2r * l2r - l2i * l2i, l4i = 2.f * l2r * l2i;
            const float l8r = l4r * l4r - l4i * l4i, l8i = 2.f * l4r * l4i;
            const float l12r = l8r * l4r - l8i * l4i;
            const float l12i = l8r * l4i + l8i * l4r;
            #pragma unroll
            for (int h = 0; h < 2; ++h) {
                float wr_, wi_;                     // lam^(12-4kq)
                if      (kq == 0) { wr_ = l12r; wi_ = l12i; }
                else if (kq == 1) { wr_ = l8r;  wi_ = l8i;  }
                else if (kq == 2) { wr_ = l4r;  wi_ = l4i;  }
                else              { wr_ = 1.f;  wi_ = 0.f;  }
                float s = 0.f;
                #pragma unroll
                for (int mi2 = 3; mi2 >= 0; --mi2) {
                    #pragma unroll
                    for (int rr = 3; rr >= 0; --rr) {
                        float own  = acc[h * 4 + mi2][ni][rr];
                        float part = __shfl_xor(own, 1);
                        s += wr_ * own + (par ? wi_ : -wi_) * part;
                        float nr = wr_ * l1r - wi_ * l1i;
                        float nI = wr_ * l1i + wi_ * l1r;
                        wr_ = nr; wi_ = nI;
                    }
                    float nr = wr_ * l12r - wi_ * l12i;
                    float nI = wr_ * l12i + wi_ * l12r;
                    wr_ = nr; wi_ = nI;
                }
                s += __shfl_xor(s, 16);             // reduce over kq
                s += __shfl_xor(s, 32);
                float other = __shfl_xor(s, 1);     // partner component
                if (kq == 0 && par == 0)
                    aggp[(size_t)(cg0 + h) * P_DIM + (bn >> 1) + ql] =
                        make_float2(s, other);
            }
        }
    }
}

// ---------------------------------------------------------------- scan
// phase2: wave-parallel carries. 1 wave per state; lane j owns chunks 4j..4j+3.
__global__ void scan_phase2p(const float2* __restrict__ agg,
                             const float2* __restrict__ lamT,
                             float2* __restrict__ carry) {
    const int w = threadIdx.x >> 6;
    const int j = threadIdx.x & 63;
    const int p = blockIdx.x * 4 + w;
    const float2 A = lamT[p];                               // lam^64
    float b2r = A.x * A.x - A.y * A.y, b2i = 2.f * A.x * A.y;
    float Br = b2r * b2r - b2i * b2i, Bi = 2.f * b2r * b2i; // lam^256
    float2 a[4];
    #pragma unroll
    for (int k = 0; k < 4; ++k) a[k] = agg[(size_t)(4 * j + k) * P_DIM + p];
    float xr = 0.f, xi = 0.f;
    #pragma unroll
    for (int k = 0; k < 4; ++k) {
        float nr = A.x * xr - A.y * xi + a[k].x;
        float ni = A.x * xi + A.y * xr + a[k].y;
        xr = nr; xi = ni;
    }
    float cr = Br, ci = Bi, vr = xr, vi = xi;
    #pragma unroll
    for (int d = 1; d < 64; d <<= 1) {
        float pvr = __shfl_up(vr, d), pvi = __shfl_up(vi, d);
        float pcr = __shfl_up(cr, d), pci = __shfl_up(ci, d);
        if (j >= d) {
            float nvr = cr * pvr - ci * pvi + vr;
            float nvi = cr * pvi + ci * pvr + vi;
            float ncr = cr * pcr - ci * pci;
            float nci = cr * pci + ci * pcr;
            vr = nvr; vi = nvi; cr = ncr; ci = nci;
        }
    }
    float sr = __shfl_up(vr, 1), si = __shfl_up(vi, 1);     // exclusive seed
    if (j == 0) { sr = 0.f; si = 0.f; }
    #pragma unroll
    for (int k = 0; k < 4; ++k) {
        carry[(size_t)(4 * j + k) * P_DIM + p] = make_float2(sr, si);
        float nr = A.x * sr - A.y * si + a[k].x;
        float ni = A.x * si + A.y * sr + a[k].y;
        sr = nr; si = ni;
    }
}

__global__ void scan_phase3(uint32_t* __restrict__ BuX,             // in-place
                            const float2* __restrict__ lam,
                            const float2* __restrict__ carry) {
    const int p = blockIdx.y * 256 + threadIdx.x;
    const int c = blockIdx.x;
    const float2 lb = lam[p];
    const float2 c0 = carry[(size_t)c * P_DIM + p];
    float xr = c0.x, xi = c0.y;
    uint32_t* b = BuX + (size_t)c * TCH * P_DIM + p;
    #pragma unroll 4
    for (int j = 0; j < TCH; ++j) {
        uint32_t v = *b;
        float nr = lb.x * xr - lb.y * xi + lo_bf(v);
        float ni = lb.x * xi + lb.y * xr + hi_bf(v);
        xr = nr; xi = ni;
        *b = pack_bf(xr, xi);
        b += P_DIM;
    }
}

// ---------------------------------------------------------------- launch
extern "C" void kernel_launch(void* const* d_in, const int* in_sizes, int n_in,
                              void* d_out, int out_size, void* d_ws, size_t ws_size,
                              hipStream_t stream) {
    float* out = (float*)d_out;  // (L,H) fp32

    char* w = (char*)d_ws;
    w += 256;
    float2* lam   = (float2*)w;  w += (size_t)P_DIM * 8;
    float2* lamT  = (float2*)w;  w += (size_t)P_DIM * 8;
    float*  d_f   = (float*)w;   w += (size_t)H_DIM * 4;
    float2* agg   = (float2*)w;  w += (size_t)NCH * P_DIM * 8;       // 2 MB
    float2* carry = (float2*)w;  w += (size_t)NCH * P_DIM * 8;       // 2 MB
    bf16*   W1t   = (bf16*)w;    w += (size_t)2 * P_DIM * H_DIM * 2; // 4 MB
    bf16*   W2t   = (bf16*)w;    w += (size_t)H_DIM * 2 * P_DIM * 2; // 4 MB
    bf16*   ub    = (bf16*)w;    w += (size_t)L_SEQ * H_DIM * 2;     // 33.5 MB
    bf16*   Xbuf  = (bf16*)w;                                        // 67 MB

    convert_u<<<(L_SEQ * H_DIM / 8) / 256, 256, 0, stream>>>(d_in[0], ub);
    prep_all<<<P_DIM, 256, 0, stream>>>(d_in[0], d_in[1], d_in[2], d_in[6],
                                        d_in[3], d_in[4], d_in[5],
                                        W1t, W2t, d_f, lam, lamT);

    // Bu(L,2P) = ub @ W1t^T  (interleaved cols) + fused chunk aggregates
    gemm256<2 * P_DIM, H_DIM, 1><<<(2 * P_DIM / 256) * (L_SEQ / 256), 512, 0, stream>>>(
        ub, W1t, Xbuf, nullptr, nullptr, nullptr, lam, agg);

    scan_phase2p<<<P_DIM / 4, 256, 0, stream>>>(agg, lamT, carry);
    scan_phase3<<<dim3(NCH, P_DIM / 256), 256, 0, stream>>>(
        (uint32_t*)Xbuf, lam, carry);

    // out = X @ W2t^T + ub*D
    gemm256<H_DIM, 2 * P_DIM, 2><<<(H_DIM / 256) * (L_SEQ / 256), 512, 0, stream>>>(
        Xbuf, W2t, nullptr, out, ub, d_f, nullptr, nullptr);
}

// Round 8
// 327.515 us; speedup vs baseline: 1.1953x; 1.1953x over previous
//
#include <hip/hip_runtime.h>
#include <hip/hip_bf16.h>
#include <stdint.h>

// S5 layer: L=16384, H=1024, P=1024. fp32 in/out. Round-15 (= round-14
// resubmitted: container infra failed twice; kernel never measured):
//   - Rounds 8-13 post-mortem: every schedule manually pinned lgkmcnt(0)+
//     sched_barrier between read-burst and MFMA-burst -> forced DS/MFMA
//     alternation (MfmaUtil stuck 28-31% across 5 structures). 4-array
//     register pipelining spills (r9, r13: VGPR cap 128 + FETCH/WRITE
//     inflation). This round removes ALL intra-tile pinning: reads issued in
//     consumption order, compiler inserts counted lgkmcnt (m97 .s evidence:
//     lgkmcnt(4/3/1/0)) -> within-wave DS||MFMA overlap with zero extra
//     registers. 3-array live set (af in-place + b0 + b1 = 64 VGPR).
//     2 barriers + counted vmcnt(8) per tile kept (staging hazards).
//   - kept: 256x256 block, BK=64, 8 waves 2Mx4N (wave tile 128x64), dbuf
//     LDS, XOR bank swizzle via pre-swizzled global src, XCD swizzle,
//     setprio around MFMA clusters, MODE1 fused chunk aggregates, MODE2
//     fused D-residual epilogue, scan kernels, convert/prep.

#define L_SEQ 16384
#define H_DIM 1024
#define P_DIM 1024
#define NCH   256
#define TCH   64

typedef __bf16 bf16x8 __attribute__((ext_vector_type(8)));
typedef float  floatx4 __attribute__((ext_vector_type(4)));
using bf16 = __hip_bfloat16;

__device__ __forceinline__ void gld_lds16(const void* g, void* l) {
    __builtin_amdgcn_global_load_lds(
        (const __attribute__((address_space(1))) uint32_t*)g,
        (__attribute__((address_space(3))) uint32_t*)l, 16, 0, 0);
}

__device__ __forceinline__ float lo_bf(uint32_t v) { return __uint_as_float(v << 16); }
__device__ __forceinline__ float hi_bf(uint32_t v) { return __uint_as_float(v & 0xffff0000u); }
__device__ __forceinline__ uint32_t pack_bf(float r, float i) {
    bf16 rb = __float2bfloat16(r), ib = __float2bfloat16(i);
    return ((uint32_t)(*(uint16_t*)&ib) << 16) | (uint32_t)(*(uint16_t*)&rb);
}

__device__ __forceinline__ float rd(const void* p, size_t i, int f) {
    return f ? ((const float*)p)[i]
             : __bfloat162float(((const bf16*)p)[i]);
}

// per-block dtype self-detect (fp32 halfwords read as bf16 show |x|>=128)
__device__ __forceinline__ int detect_f32(const uint16_t* u) {
    __shared__ int cnt;
    if (threadIdx.x == 0) cnt = 0;
    __syncthreads();
    int c = 0;
    #pragma unroll
    for (int i = 0; i < 8; ++i) {
        int e = (u[threadIdx.x * 8 + i] >> 7) & 0xFF;
        c += (e >= 134);
    }
    if (c) atomicAdd(&cnt, c);
    __syncthreads();
    return cnt > 32;
}

// ---------------------------------------------------------------- convert u
__global__ void convert_u(const void* __restrict__ uin, bf16* __restrict__ ub) {
    const int f = detect_f32((const uint16_t*)uin);
    const size_t g = (size_t)blockIdx.x * 256 + threadIdx.x;
    if (f) {
        const float4* s = (const float4*)uin + g * 2;
        float4 a = s[0], b = s[1];
        alignas(16) bf16 t[8] = {
            __float2bfloat16(a.x), __float2bfloat16(a.y),
            __float2bfloat16(a.z), __float2bfloat16(a.w),
            __float2bfloat16(b.x), __float2bfloat16(b.y),
            __float2bfloat16(b.z), __float2bfloat16(b.w)};
        ((uint4*)ub)[g] = *(const uint4*)t;
    } else {
        ((uint4*)ub)[g] = ((const uint4*)uin)[g];
    }
}

// ---------------------------------------------------------------- prep (fused)
__global__ void prep_all(const void* __restrict__ u,
                         const void* __restrict__ Lre, const void* __restrict__ Lim,
                         const void* __restrict__ lstep, const void* __restrict__ B,
                         const void* __restrict__ C, const void* __restrict__ D,
                         bf16* __restrict__ W1t, bf16* __restrict__ W2t,
                         float* __restrict__ d_f,
                         float2* __restrict__ lam, float2* __restrict__ lamT) {
    const int f = detect_f32((const uint16_t*)u);
    const int p = blockIdx.x;
    float lr = fminf(rd(Lre, p, f), -1e-4f);
    float li = rd(Lim, p, f);
    float s  = expf(rd(lstep, p, f));
    float ea = expf(lr * s);
    float lbr = ea * cosf(li * s), lbi = ea * sinf(li * s);   // lambda_bar
    float dr = lbr - 1.0f, di = lbi;
    float den = lr * lr + li * li;
    float cr = (dr * lr + di * li) / den;                     // (lb-1)/Lambda
    float ci = (di * lr - dr * li) / den;
    if (threadIdx.x == 0) {
        lam[p] = make_float2(lbr, lbi);
        float tr = lbr, ti = lbi;                             // lambda_bar^64
        #pragma unroll
        for (int q = 0; q < 6; ++q) {
            float nr = tr * tr - ti * ti, ni = 2.0f * tr * ti;
            tr = nr; ti = ni;
        }
        lamT[p] = make_float2(tr, ti);
        d_f[p] = rd(D, p, f);
    }
    for (int h = threadIdx.x; h < H_DIM; h += blockDim.x) {
        size_t base = ((size_t)p * H_DIM + h) * 2;
        float br = rd(B, base + 0, f);
        float bi = rd(B, base + 1, f);
        W1t[(size_t)(2 * p)     * H_DIM + h] = __float2bfloat16(cr * br - ci * bi);
        W1t[(size_t)(2 * p + 1) * H_DIM + h] = __float2bfloat16(cr * bi + ci * br);
    }
    const int h = blockIdx.x;
    for (int q = threadIdx.x; q < P_DIM; q += blockDim.x) {
        size_t base = ((size_t)h * P_DIM + q) * 2;
        W2t[(size_t)h * (2 * P_DIM) + 2 * q]     = __float2bfloat16( 2.0f * rd(C, base + 0, f));
        W2t[(size_t)h * (2 * P_DIM) + 2 * q + 1] = __float2bfloat16(-2.0f * rd(C, base + 1, f));
    }
}

// ---------------------------------------------------------------- GEMM 256x256
// A(M,K) bf16 rm, Bt(N,K) bf16 rm. 256x256 block, BK=64, 8 waves (2Mx4N),
// wave tile 128x64. Compiler-scheduled K-loop (counted auto-lgkmcnt),
// consumption-ordered reads, 3-array live set, 2 barriers + counted
// vmcnt(8) per tile. XOR bank swizzle via pre-swizzled global_load_lds
// source, setprio around MFMA clusters, XCD swizzle.
// MODE 1: OutBF bf16 + fused chunk aggregates (register-only weights).
// MODE 2: OutF fp32 = acc + U*Dvec, nontemporal.

#define STAGE(b, t) do {                                                      \
    const int k0_ = (t) * 64;                                                 \
    _Pragma("unroll")                                                         \
    for (int q_ = 0; q_ < 4; ++q_) {                                          \
        const int row_ = q_ * 64 + srow;                                      \
        const int g_   = sg ^ (row_ & 7);                                     \
        gld_lds16(A  + (size_t)(bm + row_) * K + k0_ + g_ * 8,                \
                  sA + (b) * 32768 + q_ * 8192 + wave * 1024);                \
        gld_lds16(Bt + (size_t)(bn + row_) * K + k0_ + g_ * 8,                \
                  sB + (b) * 32768 + q_ * 8192 + wave * 1024);                \
    } } while (0)

// load 4 A-fragment rows (mh half) into af[4][2] (in-place overwrite)
#define LDA(b, mh) do {                                                       \
    _Pragma("unroll")                                                         \
    for (int mi_ = 0; mi_ < 4; ++mi_) {                                       \
        const int row_ = wm + ((mh) * 4 + mi_) * 16 + fr;                     \
        _Pragma("unroll")                                                     \
        for (int ks_ = 0; ks_ < 2; ++ks_) {                                   \
            const int ch_ = (ks_ * 4 + kq) ^ (row_ & 7);                      \
            af[mi_][ks_] = *(const bf16x8*)(sA + (b) * 32768 + row_ * 128 + ch_ * 16); \
        } } } while (0)

// load 2 B-fragment rows (nh half) into dst[2][2]
#define LDB_TO(dst, b, nh) do {                                               \
    _Pragma("unroll")                                                         \
    for (int ni_ = 0; ni_ < 2; ++ni_) {                                       \
        const int row_ = wn + ((nh) * 2 + ni_) * 16 + fr;                     \
        _Pragma("unroll")                                                     \
        for (int ks_ = 0; ks_ < 2; ++ks_) {                                   \
            const int ch_ = (ks_ * 4 + kq) ^ (row_ & 7);                      \
            dst[ni_][ks_] = *(const bf16x8*)(sB + (b) * 32768 + row_ * 128 + ch_ * 16); \
        } } } while (0)

#define MMA(bfv, mh, nh) do {                                                 \
    __builtin_amdgcn_s_setprio(1);                                            \
    _Pragma("unroll")                                                         \
    for (int mi_ = 0; mi_ < 4; ++mi_)                                         \
        _Pragma("unroll")                                                     \
        for (int ni_ = 0; ni_ < 2; ++ni_)                                     \
            _Pragma("unroll")                                                 \
            for (int ks_ = 0; ks_ < 2; ++ks_)                                 \
                acc[(mh) * 4 + mi_][(nh) * 2 + ni_] =                         \
                    __builtin_amdgcn_mfma_f32_16x16x32_bf16(                  \
                        af[mi_][ks_], bfv[ni_][ks_],                          \
                        acc[(mh) * 4 + mi_][(nh) * 2 + ni_], 0, 0, 0);        \
    __builtin_amdgcn_s_setprio(0);                                            \
} while (0)

template <int N, int K, int MODE>
__global__ __launch_bounds__(512, 2) void gemm256(
    const bf16* __restrict__ A, const bf16* __restrict__ Bt,
    bf16* __restrict__ OutBF, float* __restrict__ OutF,
    const bf16* __restrict__ U, const float* __restrict__ Dvec,
    const float2* __restrict__ lam, float2* __restrict__ aggp) {
    constexpr int NXB = N / 256;
    constexpr int KT  = K / 64;
    __shared__ alignas(16) uint8_t sA[2 * 32768];   // [buf][256 rows][128 B]
    __shared__ alignas(16) uint8_t sB[2 * 32768];

    const int tid  = threadIdx.x;
    const int wave = tid >> 6;
    const int lane = tid & 63;
    const int bid  = blockIdx.x;
    const int xr   = bid & 7;
    const int jj   = bid >> 3;
    const int bx   = jj % NXB;
    const int by   = (jj / NXB) * 8 + xr;
    const int bm   = by * 256, bn = bx * 256;
    const int wm   = (wave >> 2) * 128, wn = (wave & 3) * 64;

    floatx4 acc[8][4] = {};

    const int fr   = lane & 15;
    const int kq   = lane >> 4;        // 0..3
    const int srow = tid >> 3;         // 0..63
    const int sg   = tid & 7;

    // prologue: stage tiles 0 and 1; vmcnt(8) = tile 0 landed.
    STAGE(0, 0);
    STAGE(1, 1);
    asm volatile("s_waitcnt vmcnt(8)" ::: "memory");
    __builtin_amdgcn_s_barrier();

    bf16x8 af[4][2], b0[2][2], b1[2][2];

    #pragma unroll 2
    for (int t = 0; t < KT; ++t) {
        const int cur = t & 1;
        // consumption-ordered reads; NO manual waits — the compiler inserts
        // counted lgkmcnt before each dependent MFMA, overlapping DS service
        // with the matrix pipe within the wave.
        LDA(cur, 0);            // af <- A half 0 (8 reads)
        LDB_TO(b0, cur, 0);     // 4 reads
        LDB_TO(b1, cur, 1);     // 4 reads
        MMA(b0, 0, 0);
        MMA(b1, 0, 1);
        LDA(cur, 1);            // af <- A half 1 (in-place, 8 reads)
        MMA(b1, 1, 1);
        MMA(b0, 1, 0);
        // all this wave's reads of buf[cur] completed (transitively via the
        // operand waits above); barrier -> safe for anyone to overwrite.
        __builtin_amdgcn_s_barrier();
        if (t + 2 < KT) {
            STAGE(cur, t + 2);
            asm volatile("s_waitcnt vmcnt(8)" ::: "memory");  // t+1 landed
        } else {
            asm volatile("s_waitcnt vmcnt(0)" ::: "memory");  // final drain
        }
        __builtin_amdgcn_s_barrier();
    }

    // ---- C write ----
    const int col0  = bn + wn + fr;
    const int rbase = bm + wm + kq * 4;
    #pragma unroll
    for (int mi = 0; mi < 8; ++mi) {
        #pragma unroll
        for (int rr = 0; rr < 4; ++rr) {
            const int row = rbase + mi * 16 + rr;
            #pragma unroll
            for (int ni = 0; ni < 4; ++ni) {
                const int c = col0 + ni * 16;
                float v = acc[mi][ni][rr];
                if (MODE == 2) {
                    float uu = __bfloat162float(U[(size_t)row * H_DIM + c]);
                    __builtin_nontemporal_store(v + uu * Dvec[c],
                                                &OutF[(size_t)row * N + c]);
                } else {
                    OutBF[(size_t)row * N + c] = __float2bfloat16(v);
                }
            }
        }
    }

    if (MODE == 1) {
        // ---- fused phase1: agg_cg(p) = sum_t lam_p^(63-t) * Bu_t(p) ----
        // Wave spans 2 chunks of 64 rows (half h: mi 4h..4h+3). Within a
        // chunk t = mi2*16 + kq*4 + rr; register-only weights: w starts at
        // lam^(12-4kq), *= lam per t-step, *= lam^12 between mi2 groups.
        // Even lane holds re, odd lane im (interleaved cols).
        const int par = fr & 1;
        const int cg0 = (bm + wm) >> 6;
        #pragma unroll
        for (int ni = 0; ni < 4; ++ni) {
            const int ql = (wn + ni * 16 + (fr & ~1)) >> 1;   // 0..127
            const float2 lb = lam[(bn >> 1) + ql];
            const float l1r = lb.x, l1i = lb.y;
            const float l2r = l1r * l1r - l1i * l1i, l2i = 2.f * l1r * l1i;
            const float l4r = l2r * l2r - l2i * l2i, l4i = 2.f * l2r * l2i;
            const float l8r = l4r * l4r - l4i * l4i, l8i = 2.f * l4r * l4i;
            const float l12r = l8r * l4r - l8i * l4i;
            const float l12i = l8r * l4i + l8i * l4r;
            #pragma unroll
            for (int h = 0; h < 2; ++h) {
                float wr_, wi_;                     // lam^(12-4kq)
                if      (kq == 0) { wr_ = l12r; wi_ = l12i; }
                else if (kq == 1) { wr_ = l8r;  wi_ = l8i;  }
                else if (kq == 2) { wr_ = l4r;  wi_ = l4i;  }
                else              { wr_ = 1.f;  wi_ = 0.f;  }
                float s = 0.f;
                #pragma unroll
                for (int mi2 = 3; mi2 >= 0; --mi2) {
                    #pragma unroll
                    for (int rr = 3; rr >= 0; --rr) {
                        float own  = acc[h * 4 + mi2][ni][rr];
                        float part = __shfl_xor(own, 1);
                        s += wr_ * own + (par ? wi_ : -wi_) * part;
                        float nr = wr_ * l1r - wi_ * l1i;
                        float nI = wr_ * l1i + wi_ * l1r;
                        wr_ = nr; wi_ = nI;
                    }
                    float nr = wr_ * l12r - wi_ * l12i;
                    float nI = wr_ * l12i + wi_ * l12r;
                    wr_ = nr; wi_ = nI;
                }
                s += __shfl_xor(s, 16);             // reduce over kq
                s += __shfl_xor(s, 32);
                float other = __shfl_xor(s, 1);     // partner component
                if (kq == 0 && par == 0)
                    aggp[(size_t)(cg0 + h) * P_DIM + (bn >> 1) + ql] =
                        make_float2(s, other);
            }
        }
    }
}

// ---------------------------------------------------------------- scan
// phase2: wave-parallel carries. 1 wave per state; lane j owns chunks 4j..4j+3.
__global__ void scan_phase2p(const float2* __restrict__ agg,
                             const float2* __restrict__ lamT,
                             float2* __restrict__ carry) {
    const int w = threadIdx.x >> 6;
    const int j = threadIdx.x & 63;
    const int p = blockIdx.x * 4 + w;
    const float2 A = lamT[p];                               // lam^64
    float b2r = A.x * A.x - A.y * A.y, b2i = 2.f * A.x * A.y;
    float Br = b2r * b2r - b2i * b2i, Bi = 2.f * b2r * b2i; // lam^256
    float2 a[4];
    #pragma unroll
    for (int k = 0; k < 4; ++k) a[k] = agg[(size_t)(4 * j + k) * P_DIM + p];
    float xr = 0.f, xi = 0.f;
    #pragma unroll
    for (int k = 0; k < 4; ++k) {
        float nr = A.x * xr - A.y * xi + a[k].x;
        float ni = A.x * xi + A.y * xr + a[k].y;
        xr = nr; xi = ni;
    }
    float cr = Br, ci = Bi, vr = xr, vi = xi;
    #pragma unroll
    for (int d = 1; d < 64; d <<= 1) {
        float pvr = __shfl_up(vr, d), pvi = __shfl_up(vi, d);
        float pcr = __shfl_up(cr, d), pci = __shfl_up(ci, d);
        if (j >= d) {
            float nvr = cr * pvr - ci * pvi + vr;
            float nvi = cr * pvi + ci * pvr + vi;
            float ncr = cr * pcr - ci * pci;
            float nci = cr * pci + ci * pcr;
            vr = nvr; vi = nvi; cr = ncr; ci = nci;
        }
    }
    float sr = __shfl_up(vr, 1), si = __shfl_up(vi, 1);     // exclusive seed
    if (j == 0) { sr = 0.f; si = 0.f; }
    #pragma unroll
    for (int k = 0; k < 4; ++k) {
        carry[(size_t)(4 * j + k) * P_DIM + p] = make_float2(sr, si);
        float nr = A.x * sr - A.y * si + a[k].x;
        float ni = A.x * si + A.y * sr + a[k].y;
        sr = nr; si = ni;
    }
}

__global__ void scan_phase3(uint32_t* __restrict__ BuX,             // in-place
                            const float2* __restrict__ lam,
                            const float2* __restrict__ carry) {
    const int p = blockIdx.y * 256 + threadIdx.x;
    const int c = blockIdx.x;
    const float2 lb = lam[p];
    const float2 c0 = carry[(size_t)c * P_DIM + p];
    float xr = c0.x, xi = c0.y;
    uint32_t* b = BuX + (size_t)c * TCH * P_DIM + p;
    #pragma unroll 4
    for (int j = 0; j < TCH; ++j) {
        uint32_t v = *b;
        float nr = lb.x * xr - lb.y * xi + lo_bf(v);
        float ni = lb.x * xi + lb.y * xr + hi_bf(v);
        xr = nr; xi = ni;
        *b = pack_bf(xr, xi);
        b += P_DIM;
    }
}

// ---------------------------------------------------------------- launch
extern "C" void kernel_launch(void* const* d_in, const int* in_sizes, int n_in,
                              void* d_out, int out_size, void* d_ws, size_t ws_size,
                              hipStream_t stream) {
    float* out = (float*)d_out;  // (L,H) fp32

    char* w = (char*)d_ws;
    w += 256;
    float2* lam   = (float2*)w;  w += (size_t)P_DIM * 8;
    float2* lamT  = (float2*)w;  w += (size_t)P_DIM * 8;
    float*  d_f   = (float*)w;   w += (size_t)H_DIM * 4;
    float2* agg   = (float2*)w;  w += (size_t)NCH * P_DIM * 8;       // 2 MB
    float2* carry = (float2*)w;  w += (size_t)NCH * P_DIM * 8;       // 2 MB
    bf16*   W1t   = (bf16*)w;    w += (size_t)2 * P_DIM * H_DIM * 2; // 4 MB
    bf16*   W2t   = (bf16*)w;    w += (size_t)H_DIM * 2 * P_DIM * 2; // 4 MB
    bf16*   ub    = (bf16*)w;    w += (size_t)L_SEQ * H_DIM * 2;     // 33.5 MB
    bf16*   Xbuf  = (bf16*)w;                                        // 67 MB

    convert_u<<<(L_SEQ * H_DIM / 8) / 256, 256, 0, stream>>>(d_in[0], ub);
    prep_all<<<P_DIM, 256, 0, stream>>>(d_in[0], d_in[1], d_in[2], d_in[6],
                                        d_in[3], d_in[4], d_in[5],
                                        W1t, W2t, d_f, lam, lamT);

    // Bu(L,2P) = ub @ W1t^T  (interleaved cols) + fused chunk aggregates
    gemm256<2 * P_DIM, H_DIM, 1><<<(2 * P_DIM / 256) * (L_SEQ / 256), 512, 0, stream>>>(
        ub, W1t, Xbuf, nullptr, nullptr, nullptr, lam, agg);

    scan_phase2p<<<P_DIM / 4, 256, 0, stream>>>(agg, lamT, carry);
    scan_phase3<<<dim3(NCH, P_DIM / 256), 256, 0, stream>>>(
        (uint32_t*)Xbuf, lam, carry);

    // out = X @ W2t^T + ub*D
    gemm256<H_DIM, 2 * P_DIM, 2><<<(H_DIM / 256) * (L_SEQ / 256), 512, 0, stream>>>(
        Xbuf, W2t, nullptr, out, ub, d_f, nullptr, nullptr);
}

// Round 9
// 320.855 us; speedup vs baseline: 1.2201x; 1.0208x over previous
//
#include <hip/hip_runtime.h>
#include <hip/hip_bf16.h>
#include <stdint.h>

// S5 layer: L=16384, H=1024, P=1024. fp32 in/out. Round-16:
//   - r8-r15 post-mortem: 28-31% MfmaUtil across 5 schedules; r15 showed
//     compiler-free is WORSE (24%). Mechanism: all waves run identical
//     phase-aligned read->wait->MFMA rhythm; barriers re-align each tile;
//     SIMD-mates are always in the same regime -> DS and MFMA pipes
//     alternate instead of overlapping.
//   - Round-16 forces ANTI-PHASE: waves 4-7 (group 1; SIMD-mate of waves
//     0-3) defer their last quadrant's MFMA across the tile boundary.
//     Fragments (afH,b0) live in registers, so Q3 of tile t-1 computes at
//     the START of tile t while group 0 issues its 16-read burst:
//       g0: [R16][M][M][R8][M][M]   g1: [M][R16][M][M][R8][M]
//     Every read burst is covered by the SIMD-mate's MFMA cluster. Same
//     registers (3-array in-place, 24 reads/tile), same 2 barriers/tile,
//     counted vmcnt(8) staging. s_setprio REMOVED (m190: hurts; would
//     starve the anti-phased reading partner).
//   - kept: 256x256 block, BK=64, 8 waves 2Mx4N (wave tile 128x64), dbuf
//     LDS, XOR bank swizzle via pre-swizzled global src, XCD swizzle,
//     MODE1 fused chunk aggregates, MODE2 fused D-residual epilogue,
//     scan kernels, convert/prep.

#define L_SEQ 16384
#define H_DIM 1024
#define P_DIM 1024
#define NCH   256
#define TCH   64

typedef __bf16 bf16x8 __attribute__((ext_vector_type(8)));
typedef float  floatx4 __attribute__((ext_vector_type(4)));
using bf16 = __hip_bfloat16;

__device__ __forceinline__ void gld_lds16(const void* g, void* l) {
    __builtin_amdgcn_global_load_lds(
        (const __attribute__((address_space(1))) uint32_t*)g,
        (__attribute__((address_space(3))) uint32_t*)l, 16, 0, 0);
}

__device__ __forceinline__ float lo_bf(uint32_t v) { return __uint_as_float(v << 16); }
__device__ __forceinline__ float hi_bf(uint32_t v) { return __uint_as_float(v & 0xffff0000u); }
__device__ __forceinline__ uint32_t pack_bf(float r, float i) {
    bf16 rb = __float2bfloat16(r), ib = __float2bfloat16(i);
    return ((uint32_t)(*(uint16_t*)&ib) << 16) | (uint32_t)(*(uint16_t*)&rb);
}

__device__ __forceinline__ float rd(const void* p, size_t i, int f) {
    return f ? ((const float*)p)[i]
             : __bfloat162float(((const bf16*)p)[i]);
}

// per-block dtype self-detect (fp32 halfwords read as bf16 show |x|>=128)
__device__ __forceinline__ int detect_f32(const uint16_t* u) {
    __shared__ int cnt;
    if (threadIdx.x == 0) cnt = 0;
    __syncthreads();
    int c = 0;
    #pragma unroll
    for (int i = 0; i < 8; ++i) {
        int e = (u[threadIdx.x * 8 + i] >> 7) & 0xFF;
        c += (e >= 134);
    }
    if (c) atomicAdd(&cnt, c);
    __syncthreads();
    return cnt > 32;
}

// ---------------------------------------------------------------- convert u
__global__ void convert_u(const void* __restrict__ uin, bf16* __restrict__ ub) {
    const int f = detect_f32((const uint16_t*)uin);
    const size_t g = (size_t)blockIdx.x * 256 + threadIdx.x;
    if (f) {
        const float4* s = (const float4*)uin + g * 2;
        float4 a = s[0], b = s[1];
        alignas(16) bf16 t[8] = {
            __float2bfloat16(a.x), __float2bfloat16(a.y),
            __float2bfloat16(a.z), __float2bfloat16(a.w),
            __float2bfloat16(b.x), __float2bfloat16(b.y),
            __float2bfloat16(b.z), __float2bfloat16(b.w)};
        ((uint4*)ub)[g] = *(const uint4*)t;
    } else {
        ((uint4*)ub)[g] = ((const uint4*)uin)[g];
    }
}

// ---------------------------------------------------------------- prep (fused)
__global__ void prep_all(const void* __restrict__ u,
                         const void* __restrict__ Lre, const void* __restrict__ Lim,
                         const void* __restrict__ lstep, const void* __restrict__ B,
                         const void* __restrict__ C, const void* __restrict__ D,
                         bf16* __restrict__ W1t, bf16* __restrict__ W2t,
                         float* __restrict__ d_f,
                         float2* __restrict__ lam, float2* __restrict__ lamT) {
    const int f = detect_f32((const uint16_t*)u);
    const int p = blockIdx.x;
    float lr = fminf(rd(Lre, p, f), -1e-4f);
    float li = rd(Lim, p, f);
    float s  = expf(rd(lstep, p, f));
    float ea = expf(lr * s);
    float lbr = ea * cosf(li * s), lbi = ea * sinf(li * s);   // lambda_bar
    float dr = lbr - 1.0f, di = lbi;
    float den = lr * lr + li * li;
    float cr = (dr * lr + di * li) / den;                     // (lb-1)/Lambda
    float ci = (di * lr - dr * li) / den;
    if (threadIdx.x == 0) {
        lam[p] = make_float2(lbr, lbi);
        float tr = lbr, ti = lbi;                             // lambda_bar^64
        #pragma unroll
        for (int q = 0; q < 6; ++q) {
            float nr = tr * tr - ti * ti, ni = 2.0f * tr * ti;
            tr = nr; ti = ni;
        }
        lamT[p] = make_float2(tr, ti);
        d_f[p] = rd(D, p, f);
    }
    for (int h = threadIdx.x; h < H_DIM; h += blockDim.x) {
        size_t base = ((size_t)p * H_DIM + h) * 2;
        float br = rd(B, base + 0, f);
        float bi = rd(B, base + 1, f);
        W1t[(size_t)(2 * p)     * H_DIM + h] = __float2bfloat16(cr * br - ci * bi);
        W1t[(size_t)(2 * p + 1) * H_DIM + h] = __float2bfloat16(cr * bi + ci * br);
    }
    const int h = blockIdx.x;
    for (int q = threadIdx.x; q < P_DIM; q += blockDim.x) {
        size_t base = ((size_t)h * P_DIM + q) * 2;
        W2t[(size_t)h * (2 * P_DIM) + 2 * q]     = __float2bfloat16( 2.0f * rd(C, base + 0, f));
        W2t[(size_t)h * (2 * P_DIM) + 2 * q + 1] = __float2bfloat16(-2.0f * rd(C, base + 1, f));
    }
}

// ---------------------------------------------------------------- GEMM 256x256
// A(M,K) bf16 rm, Bt(N,K) bf16 rm. 256x256 block, BK=64, 8 waves (2Mx4N),
// wave tile 128x64, anti-phased wave groups (group1 defers Q3 across the
// tile boundary). Counted lgkm waits, 2 barriers + counted vmcnt(8)/tile.
// XOR bank swizzle via pre-swizzled global_load_lds source, XCD swizzle.
// MODE 1: OutBF bf16 + fused chunk aggregates (register-only weights).
// MODE 2: OutF fp32 = acc + U*Dvec, nontemporal.

#define SB0 __builtin_amdgcn_sched_barrier(0)

#define STAGE(b, t) do {                                                      \
    const int k0_ = (t) * 64;                                                 \
    _Pragma("unroll")                                                         \
    for (int q_ = 0; q_ < 4; ++q_) {                                          \
        const int row_ = q_ * 64 + srow;                                      \
        const int g_   = sg ^ (row_ & 7);                                     \
        gld_lds16(A  + (size_t)(bm + row_) * K + k0_ + g_ * 8,                \
                  sA + (b) * 32768 + q_ * 8192 + wave * 1024);                \
        gld_lds16(Bt + (size_t)(bn + row_) * K + k0_ + g_ * 8,                \
                  sB + (b) * 32768 + q_ * 8192 + wave * 1024);                \
    } } while (0)

// load 4 A-fragment rows (mh half) into af[4][2] (in-place overwrite)
#define LDA(b, mh) do {                                                       \
    _Pragma("unroll")                                                         \
    for (int mi_ = 0; mi_ < 4; ++mi_) {                                       \
        const int row_ = wm + ((mh) * 4 + mi_) * 16 + fr;                     \
        _Pragma("unroll")                                                     \
        for (int ks_ = 0; ks_ < 2; ++ks_) {                                   \
            const int ch_ = (ks_ * 4 + kq) ^ (row_ & 7);                      \
            af[mi_][ks_] = *(const bf16x8*)(sA + (b) * 32768 + row_ * 128 + ch_ * 16); \
        } } } while (0)

// load 2 B-fragment rows (nh half) into dst[2][2]
#define LDB_TO(dst, b, nh) do {                                               \
    _Pragma("unroll")                                                         \
    for (int ni_ = 0; ni_ < 2; ++ni_) {                                       \
        const int row_ = wn + ((nh) * 2 + ni_) * 16 + fr;                     \
        _Pragma("unroll")                                                     \
        for (int ks_ = 0; ks_ < 2; ++ks_) {                                   \
            const int ch_ = (ks_ * 4 + kq) ^ (row_ & 7);                      \
            dst[ni_][ks_] = *(const bf16x8*)(sB + (b) * 32768 + row_ * 128 + ch_ * 16); \
        } } } while (0)

// 16-MFMA quadrant cluster (no setprio: m190 evidence + anti-phase design)
#define MMA(bfv, mh, nh) do {                                                 \
    _Pragma("unroll")                                                         \
    for (int mi_ = 0; mi_ < 4; ++mi_)                                         \
        _Pragma("unroll")                                                     \
        for (int ni_ = 0; ni_ < 2; ++ni_)                                     \
            _Pragma("unroll")                                                 \
            for (int ks_ = 0; ks_ < 2; ++ks_)                                 \
                acc[(mh) * 4 + mi_][(nh) * 2 + ni_] =                         \
                    __builtin_amdgcn_mfma_f32_16x16x32_bf16(                  \
                        af[mi_][ks_], bfv[ni_][ks_],                          \
                        acc[(mh) * 4 + mi_][(nh) * 2 + ni_], 0, 0, 0);        \
    } while (0)

template <int N, int K, int MODE>
__global__ __launch_bounds__(512, 2) void gemm256(
    const bf16* __restrict__ A, const bf16* __restrict__ Bt,
    bf16* __restrict__ OutBF, float* __restrict__ OutF,
    const bf16* __restrict__ U, const float* __restrict__ Dvec,
    const float2* __restrict__ lam, float2* __restrict__ aggp) {
    constexpr int NXB = N / 256;
    constexpr int KT  = K / 64;
    __shared__ alignas(16) uint8_t sA[2 * 32768];   // [buf][256 rows][128 B]
    __shared__ alignas(16) uint8_t sB[2 * 32768];

    const int tid  = threadIdx.x;
    const int wave = tid >> 6;
    const int lane = tid & 63;
    const int bid  = blockIdx.x;
    const int xr   = bid & 7;
    const int jj   = bid >> 3;
    const int bx   = jj % NXB;
    const int by   = (jj / NXB) * 8 + xr;
    const int bm   = by * 256, bn = bx * 256;
    const int wm   = (wave >> 2) * 128, wn = (wave & 3) * 64;
    const int grp  = (wave >> 2) & 1;   // SIMD i hosts wave i (g0) + i+4 (g1)

    floatx4 acc[8][4] = {};

    const int fr   = lane & 15;
    const int kq   = lane >> 4;        // 0..3
    const int srow = tid >> 3;         // 0..63
    const int sg   = tid & 7;

    // prologue: stage tiles 0 and 1; vmcnt(8) = tile 0 landed.
    STAGE(0, 0);
    STAGE(1, 1);
    asm volatile("s_waitcnt vmcnt(8)" ::: "memory");
    SB0;
    __builtin_amdgcn_s_barrier();

    bf16x8 af[4][2], b0[2][2], b1[2][2];

    #pragma unroll 2
    for (int t = 0; t < KT; ++t) {
        const int cur = t & 1;
        // ---- group 1 opens with the deferred Q3 of tile t-1 (af=afH_prev,
        //      b0=b0_prev still live in regs) while group 0 issues reads.
        if (grp && t > 0) { MMA(b0, 1, 0); }
        // ---- P0: 16 reads (afL 8, b0 4, b1 4); wait oldest 12
        LDA(cur, 0);
        LDB_TO(b0, cur, 0);
        LDB_TO(b1, cur, 1);
        asm volatile("s_waitcnt lgkmcnt(4)" ::: "memory");  // afL,b0 ready
        SB0;
        MMA(b0, 0, 0);
        asm volatile("s_waitcnt lgkmcnt(0)" ::: "memory");  // b1 ready
        SB0;
        MMA(b1, 0, 1);
        // ---- P2: afH (8 reads, af in-place)
        LDA(cur, 1);
        asm volatile("s_waitcnt lgkmcnt(0)" ::: "memory");  // afH ready
        SB0;
        MMA(b1, 1, 1);
        // ---- Q3: group 0 computes now; group 1 defers to tile t+1
        if (!grp) { MMA(b0, 1, 0); }
        // all reads of buf[cur] drained (lgkm 0 above) -> safe to overwrite
        __builtin_amdgcn_s_barrier();
        if (t + 2 < KT) {
            STAGE(cur, t + 2);
            asm volatile("s_waitcnt vmcnt(8)" ::: "memory");  // t+1 landed
        } else {
            asm volatile("s_waitcnt vmcnt(0)" ::: "memory");  // final drain
        }
        SB0;
        __builtin_amdgcn_s_barrier();
    }
    // group 1: final deferred quadrant of the last tile
    if (grp) { MMA(b0, 1, 0); }

    // ---- C write ----
    const int col0  = bn + wn + fr;
    const int rbase = bm + wm + kq * 4;
    #pragma unroll
    for (int mi = 0; mi < 8; ++mi) {
        #pragma unroll
        for (int rr = 0; rr < 4; ++rr) {
            const int row = rbase + mi * 16 + rr;
            #pragma unroll
            for (int ni = 0; ni < 4; ++ni) {
                const int c = col0 + ni * 16;
                float v = acc[mi][ni][rr];
                if (MODE == 2) {
                    float uu = __bfloat162float(U[(size_t)row * H_DIM + c]);
                    __builtin_nontemporal_store(v + uu * Dvec[c],
                                                &OutF[(size_t)row * N + c]);
                } else {
                    OutBF[(size_t)row * N + c] = __float2bfloat16(v);
                }
            }
        }
    }

    if (MODE == 1) {
        // ---- fused phase1: agg_cg(p) = sum_t lam_p^(63-t) * Bu_t(p) ----
        // Wave spans 2 chunks of 64 rows (half h: mi 4h..4h+3). Within a
        // chunk t = mi2*16 + kq*4 + rr; register-only weights: w starts at
        // lam^(12-4kq), *= lam per t-step, *= lam^12 between mi2 groups.
        // Even lane holds re, odd lane im (interleaved cols).
        const int par = fr & 1;
        const int cg0 = (bm + wm) >> 6;
        #pragma unroll
        for (int ni = 0; ni < 4; ++ni) {
            const int ql = (wn + ni * 16 + (fr & ~1)) >> 1;   // 0..127
            const float2 lb = lam[(bn >> 1) + ql];
            const float l1r = lb.x, l1i = lb.y;
            const float l2r = l1r * l1r - l1i * l1i, l2i = 2.f * l1r * l1i;
            const float l4r = l2r * l2r - l2i * l2i, l4i = 2.f * l2r * l2i;
            const float l8r = l4r * l4r - l4i * l4i, l8i = 2.f * l4r * l4i;
            const float l12r = l8r * l4r - l8i * l4i;
            const float l12i = l8r * l4i + l8i * l4r;
            #pragma unroll
            for (int h = 0; h < 2; ++h) {
                float wr_, wi_;                     // lam^(12-4kq)
                if      (kq == 0) { wr_ = l12r; wi_ = l12i; }
                else if (kq == 1) { wr_ = l8r;  wi_ = l8i;  }
                else if (kq == 2) { wr_ = l4r;  wi_ = l4i;  }
                else              { wr_ = 1.f;  wi_ = 0.f;  }
                float s = 0.f;
                #pragma unroll
                for (int mi2 = 3; mi2 >= 0; --mi2) {
                    #pragma unroll
                    for (int rr = 3; rr >= 0; --rr) {
                        float own  = acc[h * 4 + mi2][ni][rr];
                        float part = __shfl_xor(own, 1);
                        s += wr_ * own + (par ? wi_ : -wi_) * part;
                        float nr = wr_ * l1r - wi_ * l1i;
                        float nI = wr_ * l1i + wi_ * l1r;
                        wr_ = nr; wi_ = nI;
                    }
                    float nr = wr_ * l12r - wi_ * l12i;
                    float nI = wr_ * l12i + wi_ * l12r;
                    wr_ = nr; wi_ = nI;
                }
                s += __shfl_xor(s, 16);             // reduce over kq
                s += __shfl_xor(s, 32);
                float other = __shfl_xor(s, 1);     // partner component
                if (kq == 0 && par == 0)
                    aggp[(size_t)(cg0 + h) * P_DIM + (bn >> 1) + ql] =
                        make_float2(s, other);
            }
        }
    }
}

// ---------------------------------------------------------------- scan
// phase2: wave-parallel carries. 1 wave per state; lane j owns chunks 4j..4j+3.
__global__ void scan_phase2p(const float2* __restrict__ agg,
                             const float2* __restrict__ lamT,
                             float2* __restrict__ carry) {
    const int w = threadIdx.x >> 6;
    const int j = threadIdx.x & 63;
    const int p = blockIdx.x * 4 + w;
    const float2 A = lamT[p];                               // lam^64
    float b2r = A.x * A.x - A.y * A.y, b2i = 2.f * A.x * A.y;
    float Br = b2r * b2r - b2i * b2i, Bi = 2.f * b2r * b2i; // lam^256
    float2 a[4];
    #pragma unroll
    for (int k = 0; k < 4; ++k) a[k] = agg[(size_t)(4 * j + k) * P_DIM + p];
    float xr = 0.f, xi = 0.f;
    #pragma unroll
    for (int k = 0; k < 4; ++k) {
        float nr = A.x * xr - A.y * xi + a[k].x;
        float ni = A.x * xi + A.y * xr + a[k].y;
        xr = nr; xi = ni;
    }
    float cr = Br, ci = Bi, vr = xr, vi = xi;
    #pragma unroll
    for (int d = 1; d < 64; d <<= 1) {
        float pvr = __shfl_up(vr, d), pvi = __shfl_up(vi, d);
        float pcr = __shfl_up(cr, d), pci = __shfl_up(ci, d);
        if (j >= d) {
            float nvr = cr * pvr - ci * pvi + vr;
            float nvi = cr * pvi + ci * pvr + vi;
            float ncr = cr * pcr - ci * pci;
            float nci = cr * pci + ci * pcr;
            vr = nvr; vi = nvi; cr = ncr; ci = nci;
        }
    }
    float sr = __shfl_up(vr, 1), si = __shfl_up(vi, 1);     // exclusive seed
    if (j == 0) { sr = 0.f; si = 0.f; }
    #pragma unroll
    for (int k = 0; k < 4; ++k) {
        carry[(size_t)(4 * j + k) * P_DIM + p] = make_float2(sr, si);
        float nr = A.x * sr - A.y * si + a[k].x;
        float ni = A.x * si + A.y * sr + a[k].y;
        sr = nr; si = ni;
    }
}

__global__ void scan_phase3(uint32_t* __restrict__ BuX,             // in-place
                            const float2* __restrict__ lam,
                            const float2* __restrict__ carry) {
    const int p = blockIdx.y * 256 + threadIdx.x;
    const int c = blockIdx.x;
    const float2 lb = lam[p];
    const float2 c0 = carry[(size_t)c * P_DIM + p];
    float xr = c0.x, xi = c0.y;
    uint32_t* b = BuX + (size_t)c * TCH * P_DIM + p;
    #pragma unroll 4
    for (int j = 0; j < TCH; ++j) {
        uint32_t v = *b;
        float nr = lb.x * xr - lb.y * xi + lo_bf(v);
        float ni = lb.x * xi + lb.y * xr + hi_bf(v);
        xr = nr; xi = ni;
        *b = pack_bf(xr, xi);
        b += P_DIM;
    }
}

// ---------------------------------------------------------------- launch
extern "C" void kernel_launch(void* const* d_in, const int* in_sizes, int n_in,
                              void* d_out, int out_size, void* d_ws, size_t ws_size,
                              hipStream_t stream) {
    float* out = (float*)d_out;  // (L,H) fp32

    char* w = (char*)d_ws;
    w += 256;
    float2* lam   = (float2*)w;  w += (size_t)P_DIM * 8;
    float2* lamT  = (float2*)w;  w += (size_t)P_DIM * 8;
    float*  d_f   = (float*)w;   w += (size_t)H_DIM * 4;
    float2* agg   = (float2*)w;  w += (size_t)NCH * P_DIM * 8;       // 2 MB
    float2* carry = (float2*)w;  w += (size_t)NCH * P_DIM * 8;       // 2 MB
    bf16*   W1t   = (bf16*)w;    w += (size_t)2 * P_DIM * H_DIM * 2; // 4 MB
    bf16*   W2t   = (bf16*)w;    w += (size_t)H_DIM * 2 * P_DIM * 2; // 4 MB
    bf16*   ub    = (bf16*)w;    w += (size_t)L_SEQ * H_DIM * 2;     // 33.5 MB
    bf16*   Xbuf  = (bf16*)w;                                        // 67 MB

    convert_u<<<(L_SEQ * H_DIM / 8) / 256, 256, 0, stream>>>(d_in[0], ub);
    prep_all<<<P_DIM, 256, 0, stream>>>(d_in[0], d_in[1], d_in[2], d_in[6],
                                        d_in[3], d_in[4], d_in[5],
                                        W1t, W2t, d_f, lam, lamT);

    // Bu(L,2P) = ub @ W1t^T  (interleaved cols) + fused chunk aggregates
    gemm256<2 * P_DIM, H_DIM, 1><<<(2 * P_DIM / 256) * (L_SEQ / 256), 512, 0, stream>>>(
        ub, W1t, Xbuf, nullptr, nullptr, nullptr, lam, agg);

    scan_phase2p<<<P_DIM / 4, 256, 0, stream>>>(agg, lamT, carry);
    scan_phase3<<<dim3(NCH, P_DIM / 256), 256, 0, stream>>>(
        (uint32_t*)Xbuf, lam, carry);

    // out = X @ W2t^T + ub*D
    gemm256<H_DIM, 2 * P_DIM, 2><<<(H_DIM / 256) * (L_SEQ / 256), 512, 0, stream>>>(
        Xbuf, W2t, nullptr, out, ub, d_f, nullptr, nullptr);
}

// Round 10
// 318.413 us; speedup vs baseline: 1.2294x; 1.0077x over previous
//
#include <hip/hip_runtime.h>
#include <hip/hip_bf16.h>
#include <stdint.h>

// S5 layer: L=16384, H=1024, P=1024. fp32 in/out. Round-17:
//   - GEMM: kept BYTE-IDENTICAL to round-16 (measured best: 89.8 us/disp,
//     total 320.9). Seven schedule variants all pinned at 24-31% MfmaUtil;
//     per-tile DS traffic (256KB ~ 3100cyc) + MFMA (2480cyc) run serial and
//     the 192KB DS-read floor is intrinsic to the 2Mx4N wave tiling. Stop
//     rerolling that die; GEMM doubles as in-run control.
//   - Non-GEMM (~140us, never profiled - top-5 always gemm-only) attacked:
//     (a) convert_u + prep_all FUSED into one kernel (grid-range split) ->
//         one launch + graph gap removed;
//     (b) scan_phase3 -> uint4: 4 states/thread, 16B coalesced, 4 parallel
//         complex-FMA chains (4x ILP on the serial recurrence).
//   - kept: 256x256 block GEMM, BK=64, 8 waves 2Mx4N, dbuf LDS, XOR bank
//     swizzle via pre-swizzled global src, XCD swizzle, anti-phase grp
//     deferral (neutral, measured), MODE1 fused chunk aggregates, MODE2
//     fused D-residual epilogue, scan_phase2p.

#define L_SEQ 16384
#define H_DIM 1024
#define P_DIM 1024
#define NCH   256
#define TCH   64
#define CONV_BLOCKS 8192   // L*H/8/256

typedef __bf16 bf16x8 __attribute__((ext_vector_type(8)));
typedef float  floatx4 __attribute__((ext_vector_type(4)));
using bf16 = __hip_bfloat16;

__device__ __forceinline__ void gld_lds16(const void* g, void* l) {
    __builtin_amdgcn_global_load_lds(
        (const __attribute__((address_space(1))) uint32_t*)g,
        (__attribute__((address_space(3))) uint32_t*)l, 16, 0, 0);
}

__device__ __forceinline__ float lo_bf(uint32_t v) { return __uint_as_float(v << 16); }
__device__ __forceinline__ float hi_bf(uint32_t v) { return __uint_as_float(v & 0xffff0000u); }
__device__ __forceinline__ uint32_t pack_bf(float r, float i) {
    bf16 rb = __float2bfloat16(r), ib = __float2bfloat16(i);
    return ((uint32_t)(*(uint16_t*)&ib) << 16) | (uint32_t)(*(uint16_t*)&rb);
}

__device__ __forceinline__ float rd(const void* p, size_t i, int f) {
    return f ? ((const float*)p)[i]
             : __bfloat162float(((const bf16*)p)[i]);
}

// per-block dtype self-detect (fp32 halfwords read as bf16 show |x|>=128)
__device__ __forceinline__ int detect_f32(const uint16_t* u) {
    __shared__ int cnt;
    if (threadIdx.x == 0) cnt = 0;
    __syncthreads();
    int c = 0;
    #pragma unroll
    for (int i = 0; i < 8; ++i) {
        int e = (u[threadIdx.x * 8 + i] >> 7) & 0xFF;
        c += (e >= 134);
    }
    if (c) atomicAdd(&cnt, c);
    __syncthreads();
    return cnt > 32;
}

// ------------------------------------------------- fused convert + prep
// blocks [0, CONV_BLOCKS): convert u -> ub (bf16)
// blocks [CONV_BLOCKS, CONV_BLOCKS+P_DIM): prep weights/lambda tables
__global__ void prep_fused(const void* __restrict__ uin, bf16* __restrict__ ub,
                           const void* __restrict__ Lre, const void* __restrict__ Lim,
                           const void* __restrict__ lstep, const void* __restrict__ B,
                           const void* __restrict__ C, const void* __restrict__ D,
                           bf16* __restrict__ W1t, bf16* __restrict__ W2t,
                           float* __restrict__ d_f,
                           float2* __restrict__ lam, float2* __restrict__ lamT) {
    const int f = detect_f32((const uint16_t*)uin);
    if (blockIdx.x < CONV_BLOCKS) {
        const size_t g = (size_t)blockIdx.x * 256 + threadIdx.x;
        if (f) {
            const float4* s = (const float4*)uin + g * 2;
            float4 a = s[0], b = s[1];
            alignas(16) bf16 t[8] = {
                __float2bfloat16(a.x), __float2bfloat16(a.y),
                __float2bfloat16(a.z), __float2bfloat16(a.w),
                __float2bfloat16(b.x), __float2bfloat16(b.y),
                __float2bfloat16(b.z), __float2bfloat16(b.w)};
            ((uint4*)ub)[g] = *(const uint4*)t;
        } else {
            ((uint4*)ub)[g] = ((const uint4*)uin)[g];
        }
        return;
    }
    const int p = blockIdx.x - CONV_BLOCKS;
    float lr = fminf(rd(Lre, p, f), -1e-4f);
    float li = rd(Lim, p, f);
    float s  = expf(rd(lstep, p, f));
    float ea = expf(lr * s);
    float lbr = ea * cosf(li * s), lbi = ea * sinf(li * s);   // lambda_bar
    float dr = lbr - 1.0f, di = lbi;
    float den = lr * lr + li * li;
    float cr = (dr * lr + di * li) / den;                     // (lb-1)/Lambda
    float ci = (di * lr - dr * li) / den;
    if (threadIdx.x == 0) {
        lam[p] = make_float2(lbr, lbi);
        float tr = lbr, ti = lbi;                             // lambda_bar^64
        #pragma unroll
        for (int q = 0; q < 6; ++q) {
            float nr = tr * tr - ti * ti, ni = 2.0f * tr * ti;
            tr = nr; ti = ni;
        }
        lamT[p] = make_float2(tr, ti);
        d_f[p] = rd(D, p, f);
    }
    for (int h = threadIdx.x; h < H_DIM; h += blockDim.x) {
        size_t base = ((size_t)p * H_DIM + h) * 2;
        float br = rd(B, base + 0, f);
        float bi = rd(B, base + 1, f);
        W1t[(size_t)(2 * p)     * H_DIM + h] = __float2bfloat16(cr * br - ci * bi);
        W1t[(size_t)(2 * p + 1) * H_DIM + h] = __float2bfloat16(cr * bi + ci * br);
    }
    const int h = p;
    for (int q = threadIdx.x; q < P_DIM; q += blockDim.x) {
        size_t base = ((size_t)h * P_DIM + q) * 2;
        W2t[(size_t)h * (2 * P_DIM) + 2 * q]     = __float2bfloat16( 2.0f * rd(C, base + 0, f));
        W2t[(size_t)h * (2 * P_DIM) + 2 * q + 1] = __float2bfloat16(-2.0f * rd(C, base + 1, f));
    }
}

// ---------------------------------------------------------------- GEMM 256x256
// (byte-identical to round-16: counted lgkm waits, anti-phased wave groups,
// 2 barriers + counted vmcnt(8)/tile, XOR bank swizzle via pre-swizzled
// global_load_lds source, XCD swizzle.)
// MODE 1: OutBF bf16 + fused chunk aggregates (register-only weights).
// MODE 2: OutF fp32 = acc + U*Dvec, nontemporal.

#define SB0 __builtin_amdgcn_sched_barrier(0)

#define STAGE(b, t) do {                                                      \
    const int k0_ = (t) * 64;                                                 \
    _Pragma("unroll")                                                         \
    for (int q_ = 0; q_ < 4; ++q_) {                                          \
        const int row_ = q_ * 64 + srow;                                      \
        const int g_   = sg ^ (row_ & 7);                                     \
        gld_lds16(A  + (size_t)(bm + row_) * K + k0_ + g_ * 8,                \
                  sA + (b) * 32768 + q_ * 8192 + wave * 1024);                \
        gld_lds16(Bt + (size_t)(bn + row_) * K + k0_ + g_ * 8,                \
                  sB + (b) * 32768 + q_ * 8192 + wave * 1024);                \
    } } while (0)

// load 4 A-fragment rows (mh half) into af[4][2] (in-place overwrite)
#define LDA(b, mh) do {                                                       \
    _Pragma("unroll")                                                         \
    for (int mi_ = 0; mi_ < 4; ++mi_) {                                       \
        const int row_ = wm + ((mh) * 4 + mi_) * 16 + fr;                     \
        _Pragma("unroll")                                                     \
        for (int ks_ = 0; ks_ < 2; ++ks_) {                                   \
            const int ch_ = (ks_ * 4 + kq) ^ (row_ & 7);                      \
            af[mi_][ks_] = *(const bf16x8*)(sA + (b) * 32768 + row_ * 128 + ch_ * 16); \
        } } } while (0)

// load 2 B-fragment rows (nh half) into dst[2][2]
#define LDB_TO(dst, b, nh) do {                                               \
    _Pragma("unroll")                                                         \
    for (int ni_ = 0; ni_ < 2; ++ni_) {                                       \
        const int row_ = wn + ((nh) * 2 + ni_) * 16 + fr;                     \
        _Pragma("unroll")                                                     \
        for (int ks_ = 0; ks_ < 2; ++ks_) {                                   \
            const int ch_ = (ks_ * 4 + kq) ^ (row_ & 7);                      \
            dst[ni_][ks_] = *(const bf16x8*)(sB + (b) * 32768 + row_ * 128 + ch_ * 16); \
        } } } while (0)

// 16-MFMA quadrant cluster (no setprio: m190 evidence + anti-phase design)
#define MMA(bfv, mh, nh) do {                                                 \
    _Pragma("unroll")                                                         \
    for (int mi_ = 0; mi_ < 4; ++mi_)                                         \
        _Pragma("unroll")                                                     \
        for (int ni_ = 0; ni_ < 2; ++ni_)                                     \
            _Pragma("unroll")                                                 \
            for (int ks_ = 0; ks_ < 2; ++ks_)                                 \
                acc[(mh) * 4 + mi_][(nh) * 2 + ni_] =                         \
                    __builtin_amdgcn_mfma_f32_16x16x32_bf16(                  \
                        af[mi_][ks_], bfv[ni_][ks_],                          \
                        acc[(mh) * 4 + mi_][(nh) * 2 + ni_], 0, 0, 0);        \
    } while (0)

template <int N, int K, int MODE>
__global__ __launch_bounds__(512, 2) void gemm256(
    const bf16* __restrict__ A, const bf16* __restrict__ Bt,
    bf16* __restrict__ OutBF, float* __restrict__ OutF,
    const bf16* __restrict__ U, const float* __restrict__ Dvec,
    const float2* __restrict__ lam, float2* __restrict__ aggp) {
    constexpr int NXB = N / 256;
    constexpr int KT  = K / 64;
    __shared__ alignas(16) uint8_t sA[2 * 32768];   // [buf][256 rows][128 B]
    __shared__ alignas(16) uint8_t sB[2 * 32768];

    const int tid  = threadIdx.x;
    const int wave = tid >> 6;
    const int lane = tid & 63;
    const int bid  = blockIdx.x;
    const int xr   = bid & 7;
    const int jj   = bid >> 3;
    const int bx   = jj % NXB;
    const int by   = (jj / NXB) * 8 + xr;
    const int bm   = by * 256, bn = bx * 256;
    const int wm   = (wave >> 2) * 128, wn = (wave & 3) * 64;
    const int grp  = (wave >> 2) & 1;   // SIMD i hosts wave i (g0) + i+4 (g1)

    floatx4 acc[8][4] = {};

    const int fr   = lane & 15;
    const int kq   = lane >> 4;        // 0..3
    const int srow = tid >> 3;         // 0..63
    const int sg   = tid & 7;

    // prologue: stage tiles 0 and 1; vmcnt(8) = tile 0 landed.
    STAGE(0, 0);
    STAGE(1, 1);
    asm volatile("s_waitcnt vmcnt(8)" ::: "memory");
    SB0;
    __builtin_amdgcn_s_barrier();

    bf16x8 af[4][2], b0[2][2], b1[2][2];

    #pragma unroll 2
    for (int t = 0; t < KT; ++t) {
        const int cur = t & 1;
        // ---- group 1 opens with the deferred Q3 of tile t-1 (af=afH_prev,
        //      b0=b0_prev still live in regs) while group 0 issues reads.
        if (grp && t > 0) { MMA(b0, 1, 0); }
        // ---- P0: 16 reads (afL 8, b0 4, b1 4); wait oldest 12
        LDA(cur, 0);
        LDB_TO(b0, cur, 0);
        LDB_TO(b1, cur, 1);
        asm volatile("s_waitcnt lgkmcnt(4)" ::: "memory");  // afL,b0 ready
        SB0;
        MMA(b0, 0, 0);
        asm volatile("s_waitcnt lgkmcnt(0)" ::: "memory");  // b1 ready
        SB0;
        MMA(b1, 0, 1);
        // ---- P2: afH (8 reads, af in-place)
        LDA(cur, 1);
        asm volatile("s_waitcnt lgkmcnt(0)" ::: "memory");  // afH ready
        SB0;
        MMA(b1, 1, 1);
        // ---- Q3: group 0 computes now; group 1 defers to tile t+1
        if (!grp) { MMA(b0, 1, 0); }
        // all reads of buf[cur] drained (lgkm 0 above) -> safe to overwrite
        __builtin_amdgcn_s_barrier();
        if (t + 2 < KT) {
            STAGE(cur, t + 2);
            asm volatile("s_waitcnt vmcnt(8)" ::: "memory");  // t+1 landed
        } else {
            asm volatile("s_waitcnt vmcnt(0)" ::: "memory");  // final drain
        }
        SB0;
        __builtin_amdgcn_s_barrier();
    }
    // group 1: final deferred quadrant of the last tile
    if (grp) { MMA(b0, 1, 0); }

    // ---- C write ----
    const int col0  = bn + wn + fr;
    const int rbase = bm + wm + kq * 4;
    #pragma unroll
    for (int mi = 0; mi < 8; ++mi) {
        #pragma unroll
        for (int rr = 0; rr < 4; ++rr) {
            const int row = rbase + mi * 16 + rr;
            #pragma unroll
            for (int ni = 0; ni < 4; ++ni) {
                const int c = col0 + ni * 16;
                float v = acc[mi][ni][rr];
                if (MODE == 2) {
                    float uu = __bfloat162float(U[(size_t)row * H_DIM + c]);
                    __builtin_nontemporal_store(v + uu * Dvec[c],
                                                &OutF[(size_t)row * N + c]);
                } else {
                    OutBF[(size_t)row * N + c] = __float2bfloat16(v);
                }
            }
        }
    }

    if (MODE == 1) {
        // ---- fused phase1: agg_cg(p) = sum_t lam_p^(63-t) * Bu_t(p) ----
        // Wave spans 2 chunks of 64 rows (half h: mi 4h..4h+3). Within a
        // chunk t = mi2*16 + kq*4 + rr; register-only weights: w starts at
        // lam^(12-4kq), *= lam per t-step, *= lam^12 between mi2 groups.
        // Even lane holds re, odd lane im (interleaved cols).
        const int par = fr & 1;
        const int cg0 = (bm + wm) >> 6;
        #pragma unroll
        for (int ni = 0; ni < 4; ++ni) {
            const int ql = (wn + ni * 16 + (fr & ~1)) >> 1;   // 0..127
            const float2 lb = lam[(bn >> 1) + ql];
            const float l1r = lb.x, l1i = lb.y;
            const float l2r = l1r * l1r - l1i * l1i, l2i = 2.f * l1r * l1i;
            const float l4r = l2r * l2r - l2i * l2i, l4i = 2.f * l2r * l2i;
            const float l8r = l4r * l4r - l4i * l4i, l8i = 2.f * l4r * l4i;
            const float l12r = l8r * l4r - l8i * l4i;
            const float l12i = l8r * l4i + l8i * l4r;
            #pragma unroll
            for (int h = 0; h < 2; ++h) {
                float wr_, wi_;                     // lam^(12-4kq)
                if      (kq == 0) { wr_ = l12r; wi_ = l12i; }
                else if (kq == 1) { wr_ = l8r;  wi_ = l8i;  }
                else if (kq == 2) { wr_ = l4r;  wi_ = l4i;  }
                else              { wr_ = 1.f;  wi_ = 0.f;  }
                float s = 0.f;
                #pragma unroll
                for (int mi2 = 3; mi2 >= 0; --mi2) {
                    #pragma unroll
                    for (int rr = 3; rr >= 0; --rr) {
                        float own  = acc[h * 4 + mi2][ni][rr];
                        float part = __shfl_xor(own, 1);
                        s += wr_ * own + (par ? wi_ : -wi_) * part;
                        float nr = wr_ * l1r - wi_ * l1i;
                        float nI = wr_ * l1i + wi_ * l1r;
                        wr_ = nr; wi_ = nI;
                    }
                    float nr = wr_ * l12r - wi_ * l12i;
                    float nI = wr_ * l12i + wi_ * l12r;
                    wr_ = nr; wi_ = nI;
                }
                s += __shfl_xor(s, 16);             // reduce over kq
                s += __shfl_xor(s, 32);
                float other = __shfl_xor(s, 1);     // partner component
                if (kq == 0 && par == 0)
                    aggp[(size_t)(cg0 + h) * P_DIM + (bn >> 1) + ql] =
                        make_float2(s, other);
            }
        }
    }
}

// ---------------------------------------------------------------- scan
// phase2: wave-parallel carries. 1 wave per state; lane j owns chunks 4j..4j+3.
__global__ void scan_phase2p(const float2* __restrict__ agg,
                             const float2* __restrict__ lamT,
                             float2* __restrict__ carry) {
    const int w = threadIdx.x >> 6;
    const int j = threadIdx.x & 63;
    const int p = blockIdx.x * 4 + w;
    const float2 A = lamT[p];                               // lam^64
    float b2r = A.x * A.x - A.y * A.y, b2i = 2.f * A.x * A.y;
    float Br = b2r * b2r - b2i * b2i, Bi = 2.f * b2r * b2i; // lam^256
    float2 a[4];
    #pragma unroll
    for (int k = 0; k < 4; ++k) a[k] = agg[(size_t)(4 * j + k) * P_DIM + p];
    float xr = 0.f, xi = 0.f;
    #pragma unroll
    for (int k = 0; k < 4; ++k) {
        float nr = A.x * xr - A.y * xi + a[k].x;
        float ni = A.x * xi + A.y * xr + a[k].y;
        xr = nr; xi = ni;
    }
    float cr = Br, ci = Bi, vr = xr, vi = xi;
    #pragma unroll
    for (int d = 1; d < 64; d <<= 1) {
        float pvr = __shfl_up(vr, d), pvi = __shfl_up(vi, d);
        float pcr = __shfl_up(cr, d), pci = __shfl_up(ci, d);
        if (j >= d) {
            float nvr = cr * pvr - ci * pvi + vr;
            float nvi = cr * pvi + ci * pvr + vi;
            float ncr = cr * pcr - ci * pci;
            float nci = cr * pci + ci * pcr;
            vr = nvr; vi = nvi; cr = ncr; ci = nci;
        }
    }
    float sr = __shfl_up(vr, 1), si = __shfl_up(vi, 1);     // exclusive seed
    if (j == 0) { sr = 0.f; si = 0.f; }
    #pragma unroll
    for (int k = 0; k < 4; ++k) {
        carry[(size_t)(4 * j + k) * P_DIM + p] = make_float2(sr, si);
        float nr = A.x * sr - A.y * si + a[k].x;
        float ni = A.x * si + A.y * sr + a[k].y;
        sr = nr; si = ni;
    }
}

// phase3: in-place scan apply, uint4 form. Thread t owns states 4t..4t+3 of
// chunk blockIdx.x: 16B coalesced load/store, 4 independent FMA chains.
__global__ void scan_phase3v(uint32_t* __restrict__ Bu32,
                             const float2* __restrict__ lam,
                             const float2* __restrict__ carry) {
    const int t = threadIdx.x;          // 0..255
    const int c = blockIdx.x;           // chunk
    float lr[4], li[4], xr[4], xi[4];
    #pragma unroll
    for (int s = 0; s < 4; ++s) {
        const float2 lb = lam[4 * t + s];
        const float2 c0 = carry[(size_t)c * P_DIM + 4 * t + s];
        lr[s] = lb.x; li[s] = lb.y;
        xr[s] = c0.x; xi[s] = c0.y;
    }
    uint32_t* b = Bu32 + (size_t)c * TCH * P_DIM + 4 * t;
    #pragma unroll 4
    for (int j = 0; j < TCH; ++j) {
        alignas(16) uint32_t vv[4];
        *(uint4*)vv = *(const uint4*)b;
        #pragma unroll
        for (int s = 0; s < 4; ++s) {
            float nr = lr[s] * xr[s] - li[s] * xi[s] + lo_bf(vv[s]);
            float ni = lr[s] * xi[s] + li[s] * xr[s] + hi_bf(vv[s]);
            xr[s] = nr; xi[s] = ni;
            vv[s] = pack_bf(nr, ni);
        }
        *(uint4*)b = *(const uint4*)vv;
        b += P_DIM;
    }
}

// ---------------------------------------------------------------- launch
extern "C" void kernel_launch(void* const* d_in, const int* in_sizes, int n_in,
                              void* d_out, int out_size, void* d_ws, size_t ws_size,
                              hipStream_t stream) {
    float* out = (float*)d_out;  // (L,H) fp32

    char* w = (char*)d_ws;
    w += 256;
    float2* lam   = (float2*)w;  w += (size_t)P_DIM * 8;
    float2* lamT  = (float2*)w;  w += (size_t)P_DIM * 8;
    float*  d_f   = (float*)w;   w += (size_t)H_DIM * 4;
    float2* agg   = (float2*)w;  w += (size_t)NCH * P_DIM * 8;       // 2 MB
    float2* carry = (float2*)w;  w += (size_t)NCH * P_DIM * 8;       // 2 MB
    bf16*   W1t   = (bf16*)w;    w += (size_t)2 * P_DIM * H_DIM * 2; // 4 MB
    bf16*   W2t   = (bf16*)w;    w += (size_t)H_DIM * 2 * P_DIM * 2; // 4 MB
    bf16*   ub    = (bf16*)w;    w += (size_t)L_SEQ * H_DIM * 2;     // 33.5 MB
    bf16*   Xbuf  = (bf16*)w;                                        // 67 MB

    // fused convert(u->bf16) + weight/lambda prep: one launch
    prep_fused<<<CONV_BLOCKS + P_DIM, 256, 0, stream>>>(
        d_in[0], ub, d_in[1], d_in[2], d_in[6],
        d_in[3], d_in[4], d_in[5], W1t, W2t, d_f, lam, lamT);

    // Bu(L,2P) = ub @ W1t^T  (interleaved cols) + fused chunk aggregates
    gemm256<2 * P_DIM, H_DIM, 1><<<(2 * P_DIM / 256) * (L_SEQ / 256), 512, 0, stream>>>(
        ub, W1t, Xbuf, nullptr, nullptr, nullptr, lam, agg);

    scan_phase2p<<<P_DIM / 4, 256, 0, stream>>>(agg, lamT, carry);
    scan_phase3v<<<NCH, 256, 0, stream>>>((uint32_t*)Xbuf, lam, carry);

    // out = X @ W2t^T + ub*D
    gemm256<H_DIM, 2 * P_DIM, 2><<<(H_DIM / 256) * (L_SEQ / 256), 512, 0, stream>>>(
        Xbuf, W2t, nullptr, out, ub, d_f, nullptr, nullptr);
}